// Round 1
// baseline (663.062 us; speedup 1.0000x reference)
//
#include <hip/hip_runtime.h>

// Problem constants (Whisper medium-ish self-attn)
#define BB 8
#define TT 1024
#define DD 1280
#define HH 20
#define DHH 64
#define MM (BB*TT)      // 8192 rows
#define NQKV 3840       // fused q,k,v output columns

typedef _Float16 f16;
typedef f16 f16x8 __attribute__((ext_vector_type(8)));
typedef f16 f16x4 __attribute__((ext_vector_type(4)));
typedef float f32x4 __attribute__((ext_vector_type(4)));

// ---------------------------------------------------------------------------
// Weight transpose + fp32->f16 cast: Wt[n][k] = W[k][n], both 1280x1280
// ---------------------------------------------------------------------------
__global__ __launch_bounds__(256) void transpose_cast(const float* __restrict__ W,
                                                      f16* __restrict__ Wt) {
  __shared__ float tile[32][33];
  int tx = threadIdx.x, ty = threadIdx.y;
  int n0 = blockIdx.x * 32, k0 = blockIdx.y * 32;
#pragma unroll
  for (int i = 0; i < 32; i += 8)
    tile[ty + i][tx] = W[(size_t)(k0 + ty + i) * DD + n0 + tx];
  __syncthreads();
#pragma unroll
  for (int i = 0; i < 32; i += 8)
    Wt[(size_t)(n0 + ty + i) * DD + k0 + tx] = (f16)tile[tx][ty + i];
}

// ---------------------------------------------------------------------------
// GEMM1: [8192x1280] x [1280x3840] via A(M,K) fp32, Bt(N,K) f16.
// 128x128 tile, BK=32, 4 waves (2x2 of 64x64), mfma_f32_16x16x32_f16.
// Epilogue splits columns: n<1280 -> q (f16, * 0.125 scale, +bq)
//                          1280..2559 -> k_cache fp32
//                          2560..3839 -> v_cache fp32 (+bv)
// ---------------------------------------------------------------------------
#define AS_LD 40   // 32 + 8 pad (80B rows: 16B-aligned, conflict-free b128)

__global__ __launch_bounds__(256) void gemm_qkv(const float* __restrict__ X,
                                                const f16* __restrict__ Wt,
                                                const float* __restrict__ bq,
                                                const float* __restrict__ bv,
                                                f16* __restrict__ qout,
                                                float* __restrict__ kout,
                                                float* __restrict__ vout) {
  __shared__ f16 As[128][AS_LD];
  __shared__ f16 Bs[128][AS_LD];
  int tid = threadIdx.x;
  int m0 = blockIdx.y * 128;
  int n0 = blockIdx.x * 128;
  int w = tid >> 6, lane = tid & 63;
  int wm = (w >> 1) * 64, wn = (w & 1) * 64;
  int col16 = lane & 15, quad = lane >> 4;

  f32x4 acc[4][4] = {};

  for (int k0 = 0; k0 < DD; k0 += 32) {
    // stage A: 128x32 fp32 -> f16 (1024 float4 chunks)
#pragma unroll
    for (int i = 0; i < 4; ++i) {
      int c = tid + i * 256;
      int row = c >> 3, cc = (c & 7) * 4;
      float4 v = *(const float4*)&X[(size_t)(m0 + row) * DD + k0 + cc];
      f16x4 h4 = {(f16)v.x, (f16)v.y, (f16)v.z, (f16)v.w};
      *(f16x4*)&As[row][cc] = h4;
    }
    // stage B: 128x32 f16 (512 chunks of 8)
#pragma unroll
    for (int i = 0; i < 2; ++i) {
      int c = tid + i * 256;
      int row = c >> 2, cc = (c & 3) * 8;
      *(f16x8*)&Bs[row][cc] = *(const f16x8*)&Wt[(size_t)(n0 + row) * DD + k0 + cc];
    }
    __syncthreads();

    f16x8 af[4], bfrag[4];
#pragma unroll
    for (int mi = 0; mi < 4; ++mi) af[mi] = *(f16x8*)&As[wm + mi * 16 + col16][quad * 8];
#pragma unroll
    for (int ni = 0; ni < 4; ++ni) bfrag[ni] = *(f16x8*)&Bs[wn + ni * 16 + col16][quad * 8];
#pragma unroll
    for (int mi = 0; mi < 4; ++mi)
#pragma unroll
      for (int ni = 0; ni < 4; ++ni)
        acc[mi][ni] = __builtin_amdgcn_mfma_f32_16x16x32_f16(af[mi], bfrag[ni], acc[mi][ni], 0, 0, 0);
    __syncthreads();
  }

  int region = n0 / DD;   // uniform per block (128 | 1280)
  int nbase = n0 % DD;
#pragma unroll
  for (int mi = 0; mi < 4; ++mi) {
#pragma unroll
    for (int ni = 0; ni < 4; ++ni) {
      int n = nbase + wn + ni * 16 + col16;
      float bias_q = (region == 0) ? bq[n] : 0.f;
      float bias_v = (region == 2) ? bv[n] : 0.f;
#pragma unroll
      for (int r = 0; r < 4; ++r) {
        int m = m0 + wm + mi * 16 + quad * 4 + r;
        float val = acc[mi][ni][r];
        if (region == 0) {
          qout[(size_t)m * DD + n] = (f16)((val + bias_q) * 0.125f);  // scale^2 = 1/8 folded into q
        } else if (region == 1) {
          kout[(size_t)m * DD + n] = val;
        } else {
          vout[(size_t)m * DD + n] = val + bias_v;
        }
      }
    }
  }
}

// ---------------------------------------------------------------------------
// Flash attention: grid (T/64, H, B), 256 threads (4 waves).
// Wave w owns q-rows [w*16, w*16+16) of its 64-row q-tile.
// K/V tiles (64 keys) staged fp32->f16 (V transposed). Online softmax state
// per q-row in LDS. O accumulated in C-layout regs, divided by l at the end.
// ---------------------------------------------------------------------------
#define VLD 72   // 64 + 8 pad, 144B rows (16B aligned)

__global__ __launch_bounds__(256) void attn(const f16* __restrict__ Q,     // scaled q, (B,T,D)
                                            const float* __restrict__ Kc,  // k_cache fp32 (B,T,D)
                                            const float* __restrict__ Vc,  // v_cache fp32 (B,T,D)
                                            f16* __restrict__ WV) {        // (B,T,D) f16
  __shared__ f16 Qs[64][VLD];
  __shared__ f16 Ks[64][VLD];
  __shared__ f16 Vst[64][VLD];       // Vst[d][j]
  __shared__ float Sw[4][16][68];    // per-wave S scratch
  __shared__ f16 Pw[4][16][VLD];     // per-wave P (A-layout friendly)
  __shared__ float mstate[64], lstate[64], alphas[64];

  int qt = blockIdx.x, h = blockIdx.y, b = blockIdx.z;
  int tid = threadIdx.x, w = tid >> 6, lane = tid & 63;
  int col16 = lane & 15, quad = lane >> 4;
  size_t head_off = (size_t)b * TT * DD + (size_t)h * DHH;

  // stage Q tile (f16, already scaled)
#pragma unroll
  for (int i = 0; i < 2; ++i) {
    int c = tid + i * 256;
    int row = c >> 3, cc = (c & 7) * 8;
    *(f16x8*)&Qs[row][cc] = *(const f16x8*)&Q[head_off + (size_t)(qt * 64 + row) * DD + cc];
  }
  if (tid < 64) { mstate[tid] = -1e30f; lstate[tid] = 0.f; }
  f32x4 accO[4] = {};
  __syncthreads();

  for (int jt = 0; jt <= qt; ++jt) {
    // stage K (row-major) and V (transposed) tiles, fp32 -> f16
#pragma unroll
    for (int i = 0; i < 4; ++i) {
      int c = tid + i * 256;
      int row = c >> 4, cc = (c & 15) * 4;
      size_t g = head_off + (size_t)(jt * 64 + row) * DD + cc;
      float4 kv = *(const float4*)&Kc[g];
      f16x4 k4 = {(f16)kv.x, (f16)kv.y, (f16)kv.z, (f16)kv.w};
      *(f16x4*)&Ks[row][cc] = k4;
      float4 vv = *(const float4*)&Vc[g];
      Vst[cc + 0][row] = (f16)vv.x;
      Vst[cc + 1][row] = (f16)vv.y;
      Vst[cc + 2][row] = (f16)vv.z;
      Vst[cc + 3][row] = (f16)vv.w;
    }
    __syncthreads();

    // S = Q K^T  (16 q-rows x 64 j per wave)
    f32x4 s[4] = {};
#pragma unroll
    for (int jsub = 0; jsub < 4; ++jsub) {
#pragma unroll
      for (int kh = 0; kh < 2; ++kh) {
        f16x8 aq = *(f16x8*)&Qs[w * 16 + col16][kh * 32 + quad * 8];
        f16x8 bk = *(f16x8*)&Ks[jsub * 16 + col16][kh * 32 + quad * 8];
        s[jsub] = __builtin_amdgcn_mfma_f32_16x16x32_f16(aq, bk, s[jsub], 0, 0, 0);
      }
    }
    // spill S to LDS with causal mask (C layout: row=quad*4+r, col=lane&15)
    bool diag = (jt == qt);
#pragma unroll
    for (int jsub = 0; jsub < 4; ++jsub) {
#pragma unroll
      for (int r = 0; r < 4; ++r) {
        int qrow = quad * 4 + r;
        int jcol = jsub * 16 + col16;
        float sv = s[jsub][r];
        if (diag && jcol > (w * 16 + qrow)) sv = -1e30f;
        Sw[w][qrow][jcol] = sv;
      }
    }
    // online softmax: lane handles row = lane>>2, 16 j's at part = lane&3
    {
      int row = lane >> 2, part = lane & 3;
      float vals[16];
      float mx = -1e30f;
#pragma unroll
      for (int u = 0; u < 16; ++u) {
        vals[u] = Sw[w][row][part * 16 + u];
        mx = fmaxf(mx, vals[u]);
      }
      mx = fmaxf(mx, __shfl_xor(mx, 1));
      mx = fmaxf(mx, __shfl_xor(mx, 2));
      float mprev = mstate[w * 16 + row];
      float mnew = fmaxf(mprev, mx);
      float alpha = __expf(mprev - mnew);
      float ssum = 0.f;
#pragma unroll
      for (int u = 0; u < 16; ++u) {
        float p = __expf(vals[u] - mnew);
        ssum += p;
        Pw[w][row][part * 16 + u] = (f16)p;
      }
      ssum += __shfl_xor(ssum, 1);
      ssum += __shfl_xor(ssum, 2);
      if (part == 0) {
        lstate[w * 16 + row] = lstate[w * 16 + row] * alpha + ssum;
        mstate[w * 16 + row] = mnew;
        alphas[w * 16 + row] = alpha;
      }
    }
    // rescale O, then O += P V
#pragma unroll
    for (int dsub = 0; dsub < 4; ++dsub)
#pragma unroll
      for (int r = 0; r < 4; ++r)
        accO[dsub][r] *= alphas[w * 16 + quad * 4 + r];
#pragma unroll
    for (int dsub = 0; dsub < 4; ++dsub) {
#pragma unroll
      for (int kh = 0; kh < 2; ++kh) {
        f16x8 ap = *(f16x8*)&Pw[w][col16][kh * 32 + quad * 8];
        f16x8 bv = *(f16x8*)&Vst[dsub * 16 + col16][kh * 32 + quad * 8];
        accO[dsub] = __builtin_amdgcn_mfma_f32_16x16x32_f16(ap, bv, accO[dsub], 0, 0, 0);
      }
    }
    __syncthreads();   // protect Ks/Vst before next stage
  }

  // epilogue: divide by l, store wv (f16) in (B,T,D)
#pragma unroll
  for (int dsub = 0; dsub < 4; ++dsub) {
#pragma unroll
    for (int r = 0; r < 4; ++r) {
      int qrow = w * 16 + quad * 4 + r;
      float o = accO[dsub][r] / lstate[qrow];
      WV[head_off + (size_t)(qt * 64 + qrow) * DD + dsub * 16 + col16] = (f16)o;
    }
  }
}

// ---------------------------------------------------------------------------
// GEMM2: out = wv(f16, M x K) x Wo_t(f16, N x K) + bo, fp32 out.
// ---------------------------------------------------------------------------
__global__ __launch_bounds__(256) void gemm_out(const f16* __restrict__ A,
                                                const f16* __restrict__ Wt,
                                                const float* __restrict__ bo,
                                                float* __restrict__ out) {
  __shared__ f16 As[128][AS_LD];
  __shared__ f16 Bs[128][AS_LD];
  int tid = threadIdx.x;
  int m0 = blockIdx.y * 128;
  int n0 = blockIdx.x * 128;
  int w = tid >> 6, lane = tid & 63;
  int wm = (w >> 1) * 64, wn = (w & 1) * 64;
  int col16 = lane & 15, quad = lane >> 4;

  f32x4 acc[4][4] = {};

  for (int k0 = 0; k0 < DD; k0 += 32) {
#pragma unroll
    for (int i = 0; i < 2; ++i) {
      int c = tid + i * 256;
      int row = c >> 2, cc = (c & 3) * 8;
      *(f16x8*)&As[row][cc] = *(const f16x8*)&A[(size_t)(m0 + row) * DD + k0 + cc];
      *(f16x8*)&Bs[row][cc] = *(const f16x8*)&Wt[(size_t)(n0 + row) * DD + k0 + cc];
    }
    __syncthreads();

    f16x8 af[4], bfrag[4];
#pragma unroll
    for (int mi = 0; mi < 4; ++mi) af[mi] = *(f16x8*)&As[wm + mi * 16 + col16][quad * 8];
#pragma unroll
    for (int ni = 0; ni < 4; ++ni) bfrag[ni] = *(f16x8*)&Bs[wn + ni * 16 + col16][quad * 8];
#pragma unroll
    for (int mi = 0; mi < 4; ++mi)
#pragma unroll
      for (int ni = 0; ni < 4; ++ni)
        acc[mi][ni] = __builtin_amdgcn_mfma_f32_16x16x32_f16(af[mi], bfrag[ni], acc[mi][ni], 0, 0, 0);
    __syncthreads();
  }

#pragma unroll
  for (int mi = 0; mi < 4; ++mi) {
#pragma unroll
    for (int ni = 0; ni < 4; ++ni) {
      int n = n0 + wn + ni * 16 + col16;
      float bias = bo[n];
#pragma unroll
      for (int r = 0; r < 4; ++r) {
        int m = m0 + wm + mi * 16 + quad * 4 + r;
        out[(size_t)m * DD + n] = acc[mi][ni][r] + bias;
      }
    }
  }
}

// ---------------------------------------------------------------------------
extern "C" void kernel_launch(void* const* d_in, const int* in_sizes, int n_in,
                              void* d_out, int out_size, void* d_ws, size_t ws_size,
                              hipStream_t stream) {
  const float* x  = (const float*)d_in[0];
  // d_in[1], d_in[2] (k_cache/v_cache inputs) are zeros and fully overwritten.
  const float* Wq = (const float*)d_in[4];
  const float* bq = (const float*)d_in[5];
  const float* Wk = (const float*)d_in[6];
  const float* Wv = (const float*)d_in[7];
  const float* bv = (const float*)d_in[8];
  const float* Wo = (const float*)d_in[9];
  const float* bo = (const float*)d_in[10];

  float* out  = (float*)d_out;
  float* kout = out + (size_t)MM * DD;        // k_cache output region
  float* vout = out + 2 * (size_t)MM * DD;    // v_cache output region

  // workspace layout (bytes):
  //   wqkv_t : 3840*1280*2 = 9,830,400
  //   wo_t   : 1280*1280*2 = 3,276,800
  //   qbuf   : 8192*1280*2 = 20,971,520  (scaled q, f16)
  //   wvbuf  : 8192*1280*2 = 20,971,520  (attention output, f16)
  char* ws = (char*)d_ws;
  f16* wqkv_t = (f16*)(ws);
  f16* wo_t   = (f16*)(ws + 9830400);
  f16* qbuf   = (f16*)(ws + 13107200);
  f16* wvbuf  = (f16*)(ws + 34078720);

  dim3 tb(32, 8), tg(40, 40);
  transpose_cast<<<tg, tb, 0, stream>>>(Wq, wqkv_t);
  transpose_cast<<<tg, tb, 0, stream>>>(Wk, wqkv_t + 1280 * 1280);
  transpose_cast<<<tg, tb, 0, stream>>>(Wv, wqkv_t + 2 * 1280 * 1280);
  transpose_cast<<<tg, tb, 0, stream>>>(Wo, wo_t);

  gemm_qkv<<<dim3(30, 64), 256, 0, stream>>>(x, wqkv_t, bq, bv, qbuf, kout, vout);
  attn<<<dim3(TT / 64, HH, BB), 256, 0, stream>>>(qbuf, kout, vout, wvbuf);
  gemm_out<<<dim3(10, 64), 256, 0, stream>>>(wvbuf, wo_t, bo, out);
}

// Round 2
// 506.590 us; speedup vs baseline: 1.3089x; 1.3089x over previous
//
#include <hip/hip_runtime.h>

// Whisper-style self-attention, B=8 T=1024 D=1280 H=20 DH=64, fp32 I/O.
#define BB 8
#define TT 1024
#define DD 1280
#define HH 20
#define DHH 64
#define MM (BB*TT)      // 8192 rows

typedef _Float16 f16;
typedef f16 f16x8 __attribute__((ext_vector_type(8)));
typedef f16 f16x4 __attribute__((ext_vector_type(4)));
typedef float f32x4 __attribute__((ext_vector_type(4)));

// async global->LDS, 16B per lane. LDS dest = wave-uniform base + lane*16.
__device__ __forceinline__ void async16(const f16* g, f16* l) {
  __builtin_amdgcn_global_load_lds((const __attribute__((address_space(1))) void*)g,
                                   (__attribute__((address_space(3))) void*)l, 16, 0, 0);
}

// ---------------------------------------------------------------------------
// Weight transpose + fp32->f16 cast: Wt[n][k] = W[k][n], 1280x1280
// ---------------------------------------------------------------------------
__global__ __launch_bounds__(256) void transpose_cast(const float* __restrict__ W,
                                                      f16* __restrict__ Wt) {
  __shared__ float tile[32][33];
  int tx = threadIdx.x, ty = threadIdx.y;
  int n0 = blockIdx.x * 32, k0 = blockIdx.y * 32;
#pragma unroll
  for (int i = 0; i < 32; i += 8)
    tile[ty + i][tx] = W[(size_t)(k0 + ty + i) * DD + n0 + tx];
  __syncthreads();
#pragma unroll
  for (int i = 0; i < 32; i += 8)
    Wt[(size_t)(n0 + ty + i) * DD + k0 + tx] = (f16)tile[tx][ty + i];
}

// ---------------------------------------------------------------------------
// x fp32 -> f16 row-major copy
// ---------------------------------------------------------------------------
__global__ __launch_bounds__(256) void cvt_x(const float* __restrict__ src,
                                             f16* __restrict__ dst) {
  int i = blockIdx.x * 256 + threadIdx.x;   // 8 elems per thread
  float4 a = *(const float4*)&src[(size_t)i * 8];
  float4 b = *(const float4*)&src[(size_t)i * 8 + 4];
  f16x8 h = {(f16)a.x,(f16)a.y,(f16)a.z,(f16)a.w,(f16)b.x,(f16)b.y,(f16)b.z,(f16)b.w};
  *(f16x8*)&dst[(size_t)i * 8] = h;
}

// ---------------------------------------------------------------------------
// m97-style GEMM core: 128x128 tile, BK=64, global_load_lds, swizzled LDS.
// A (M,K) f16 row-major, Bt (N,K) f16 row-major. Swizzle: LDS chunk
// (row, c) holds global chunk c ^ (row&7); frag reads XOR back -> 2-way free.
// ---------------------------------------------------------------------------
__global__ __launch_bounds__(256) void gemm_qkv(const f16* __restrict__ Xh,
                                                const f16* __restrict__ Wt,
                                                const float* __restrict__ bq,
                                                const float* __restrict__ bv,
                                                f16* __restrict__ qbuf,
                                                float* __restrict__ kout,
                                                float* __restrict__ vout,
                                                f16* __restrict__ vt16,
                                                int use_vt) {
  __shared__ f16 As[128 * 64];
  __shared__ f16 Bs[128 * 64];
  int tid = threadIdx.x, w = tid >> 6, lane = tid & 63;
  int m0 = blockIdx.y * 128, n0 = blockIdx.x * 128;
  int col16 = lane & 15, quad = lane >> 4;
  int wm = (w >> 1) * 64, wn = (w & 1) * 64;
  int rowS[4], cgS[4];
#pragma unroll
  for (int t = 0; t < 4; ++t) {
    int L = w * 256 + t * 64 + lane;
    rowS[t] = L >> 3;
    cgS[t] = (L & 7) ^ ((L >> 3) & 7);
  }
  f32x4 acc[4][4] = {};
  for (int k0 = 0; k0 < DD; k0 += 64) {
#pragma unroll
    for (int t = 0; t < 4; ++t) {
      async16(&Xh[(size_t)(m0 + rowS[t]) * DD + k0 + cgS[t] * 8], &As[(w * 4 + t) * 512]);
      async16(&Wt[(size_t)(n0 + rowS[t]) * DD + k0 + cgS[t] * 8], &Bs[(w * 4 + t) * 512]);
    }
    __syncthreads();
    f16x8 af[4][2], bf[4][2];
#pragma unroll
    for (int mi = 0; mi < 4; ++mi) {
      int m = wm + mi * 16 + col16;
#pragma unroll
      for (int kh = 0; kh < 2; ++kh)
        af[mi][kh] = *(f16x8*)&As[m * 64 + (((kh * 4 + quad) ^ (m & 7)) * 8)];
    }
#pragma unroll
    for (int ni = 0; ni < 4; ++ni) {
      int n = wn + ni * 16 + col16;
#pragma unroll
      for (int kh = 0; kh < 2; ++kh)
        bf[ni][kh] = *(f16x8*)&Bs[n * 64 + (((kh * 4 + quad) ^ (n & 7)) * 8)];
    }
#pragma unroll
    for (int kh = 0; kh < 2; ++kh)
#pragma unroll
      for (int mi = 0; mi < 4; ++mi)
#pragma unroll
        for (int ni = 0; ni < 4; ++ni)
          acc[mi][ni] = __builtin_amdgcn_mfma_f32_16x16x32_f16(af[mi][kh], bf[ni][kh], acc[mi][ni], 0, 0, 0);
    __syncthreads();
  }

  int region = n0 / DD, nb = n0 - region * DD;
  int bB = m0 >> 10;            // 128-row tiles never cross a batch boundary
  int t0 = m0 & 1023;
  if (region == 0) {            // q -> qbuf f16 [b][h][t][d], *0.125 (=scale^2), +bq
#pragma unroll
    for (int mi = 0; mi < 4; ++mi)
#pragma unroll
      for (int ni = 0; ni < 4; ++ni) {
        int n = nb + wn + ni * 16 + col16;
        int hh = n >> 6, dd = n & 63;
        float bb = bq[n];
        size_t base = (((size_t)bB * HH + hh) * TT + (t0 + wm + mi * 16 + quad * 4)) * 64 + dd;
#pragma unroll
        for (int r = 0; r < 4; ++r)
          qbuf[base + (size_t)r * 64] = (f16)((acc[mi][ni][r] + bb) * 0.125f);
      }
  } else if (region == 1) {     // k -> k_cache fp32
#pragma unroll
    for (int mi = 0; mi < 4; ++mi)
#pragma unroll
      for (int ni = 0; ni < 4; ++ni) {
        int n = nb + wn + ni * 16 + col16;
        size_t mrow = (size_t)(m0 + wm + mi * 16 + quad * 4) * DD + n;
#pragma unroll
        for (int r = 0; r < 4; ++r)
          kout[mrow + (size_t)r * DD] = acc[mi][ni][r];
      }
  } else {                      // v -> v_cache fp32 (+bv), optional Vt16 f16 [b][h][d][t]
#pragma unroll
    for (int mi = 0; mi < 4; ++mi)
#pragma unroll
      for (int ni = 0; ni < 4; ++ni) {
        int n = nb + wn + ni * 16 + col16;
        int hh = n >> 6, dd = n & 63;
        float bb = bv[n];
        size_t mrow = (size_t)(m0 + wm + mi * 16 + quad * 4) * DD + n;
        f16x4 pk;
#pragma unroll
        for (int r = 0; r < 4; ++r) {
          float vv = acc[mi][ni][r] + bb;
          vout[mrow + (size_t)r * DD] = vv;
          pk[r] = (f16)vv;
        }
        if (use_vt)
          *(f16x4*)&vt16[(((size_t)bB * HH + hh) * 64 + dd) * TT + t0 + wm + mi * 16 + quad * 4] = pk;
      }
  }
}

// ---------------------------------------------------------------------------
// Flash attention v2: grid (8, 20, 8), 4 waves, 128 q-rows/block (32/wave).
// S^T = K*Q^T so softmax reduces with 2 shuffles; m/l in registers;
// P through LDS once (2-way writes); O = P*V with vectorized frag reads.
// ---------------------------------------------------------------------------
__global__ __launch_bounds__(256) void attn(const f16* __restrict__ qbuf,
                                            const float* __restrict__ kout,
                                            const float* __restrict__ vout,
                                            const f16* __restrict__ vt16,
                                            f16* __restrict__ wv,
                                            int use_vt) {
  __shared__ f16 Ks[64][72];
  __shared__ f16 Vt[64][72];        // Vt[d][j]
  __shared__ f16 Pw[4][32][72];     // per-wave P[q][j]
  int qt = blockIdx.x, h = blockIdx.y, b = blockIdx.z;
  int tid = threadIdx.x, w = tid >> 6, lane = tid & 63;
  int col16 = lane & 15, quad = lane >> 4;

  const f16* Qh = qbuf + (((size_t)b * HH + h) * TT + qt * 128 + w * 32) * 64;
  f16x8 qf[2][2];
#pragma unroll
  for (int ni = 0; ni < 2; ++ni)
#pragma unroll
    for (int kh = 0; kh < 2; ++kh)
      qf[ni][kh] = *(const f16x8*)&Qh[(ni * 16 + col16) * 64 + kh * 32 + quad * 8];

  float m_run[2] = {-1e30f, -1e30f}, l_run[2] = {0.f, 0.f};
  f32x4 accO[2][4] = {};
  int jt_end = 2 * qt + 2;
  int my_end = 2 * qt + 1 + (w >> 1);
  const float* Kg = kout + ((size_t)b * TT) * DD + h * 64;
  const float* Vg = vout + ((size_t)b * TT) * DD + h * 64;
  const f16* Vtg = vt16 + (((size_t)b * HH + h) * 64) * TT;

  for (int jt = 0; jt < jt_end; ++jt) {
    // ---- stage K (row-major) and V^T ----
#pragma unroll
    for (int i = 0; i < 4; ++i) {
      int g = tid + i * 256;
      int j = g >> 4, c4 = (g & 15) * 4;
      float4 kv = *(const float4*)&Kg[(size_t)(jt * 64 + j) * DD + c4];
      f16x4 k4 = {(f16)kv.x, (f16)kv.y, (f16)kv.z, (f16)kv.w};
      *(f16x4*)&Ks[j][c4] = k4;
    }
    if (use_vt) {
#pragma unroll
      for (int i = 0; i < 2; ++i) {
        int c2 = tid + i * 256;
        int d = c2 >> 3, jc = (c2 & 7) * 8;
        *(f16x8*)&Vt[d][jc] = *(const f16x8*)&Vtg[(size_t)d * TT + jt * 64 + jc];
      }
    } else {
#pragma unroll
      for (int i = 0; i < 4; ++i) {
        int g = tid + i * 256;
        int j = g >> 4, c4 = (g & 15) * 4;
        float4 vv = *(const float4*)&Vg[(size_t)(jt * 64 + j) * DD + c4];
        Vt[c4 + 0][j] = (f16)vv.x; Vt[c4 + 1][j] = (f16)vv.y;
        Vt[c4 + 2][j] = (f16)vv.z; Vt[c4 + 3][j] = (f16)vv.w;
      }
    }
    __syncthreads();

    if (jt < my_end) {
      // S^T[j][q] = K*Q^T : lane holds j = mj*16+quad*4+r, q = ni*16+col16
      f32x4 s[4][2] = {};
#pragma unroll
      for (int mj = 0; mj < 4; ++mj)
#pragma unroll
        for (int kh = 0; kh < 2; ++kh) {
          f16x8 ak = *(f16x8*)&Ks[mj * 16 + col16][kh * 32 + quad * 8];
#pragma unroll
          for (int ni = 0; ni < 2; ++ni)
            s[mj][ni] = __builtin_amdgcn_mfma_f32_16x16x32_f16(ak, qf[ni][kh], s[mj][ni], 0, 0, 0);
        }
      // causal mask (only on diagonal-touching tiles)
      if (jt * 64 + 63 > qt * 128 + w * 32) {
#pragma unroll
        for (int mj = 0; mj < 4; ++mj)
#pragma unroll
          for (int ni = 0; ni < 2; ++ni) {
            int qg = qt * 128 + w * 32 + ni * 16 + col16;
#pragma unroll
            for (int r = 0; r < 4; ++r) {
              int jg = jt * 64 + mj * 16 + quad * 4 + r;
              if (jg > qg) s[mj][ni][r] = -1e30f;
            }
          }
      }
      // online softmax, in-register (reduction over j = regs + 2 shuffles)
      float alpha[2];
#pragma unroll
      for (int ni = 0; ni < 2; ++ni) {
        float mx = -1e30f;
#pragma unroll
        for (int mj = 0; mj < 4; ++mj)
#pragma unroll
          for (int r = 0; r < 4; ++r) mx = fmaxf(mx, s[mj][ni][r]);
        mx = fmaxf(mx, __shfl_xor(mx, 16));
        mx = fmaxf(mx, __shfl_xor(mx, 32));
        float mnew = fmaxf(m_run[ni], mx);
        float al = __expf(m_run[ni] - mnew);
        float ssum = 0.f;
#pragma unroll
        for (int mj = 0; mj < 4; ++mj)
#pragma unroll
          for (int r = 0; r < 4; ++r) {
            float p = __expf(s[mj][ni][r] - mnew);
            ssum += p;
            Pw[w][ni * 16 + col16][mj * 16 + quad * 4 + r] = (f16)p;
          }
        ssum += __shfl_xor(ssum, 16);
        ssum += __shfl_xor(ssum, 32);
        l_run[ni] = l_run[ni] * al + ssum;
        m_run[ni] = mnew;
        alpha[ni] = al;
      }
      // rescale O rows (alpha redistributed col16-lanes -> quad*4+r regs)
#pragma unroll
      for (int mi = 0; mi < 2; ++mi)
#pragma unroll
        for (int r = 0; r < 4; ++r) {
          float a_o = __shfl(alpha[mi], quad * 4 + r);
#pragma unroll
          for (int dsub = 0; dsub < 4; ++dsub) accO[mi][dsub][r] *= a_o;
        }
      // O += P*V
      f16x8 ap[2][2];
#pragma unroll
      for (int mi = 0; mi < 2; ++mi)
#pragma unroll
        for (int kh = 0; kh < 2; ++kh)
          ap[mi][kh] = *(f16x8*)&Pw[w][mi * 16 + col16][kh * 32 + quad * 8];
#pragma unroll
      for (int dsub = 0; dsub < 4; ++dsub)
#pragma unroll
        for (int kh = 0; kh < 2; ++kh) {
          f16x8 bvv = *(f16x8*)&Vt[dsub * 16 + col16][kh * 32 + quad * 8];
#pragma unroll
          for (int mi = 0; mi < 2; ++mi)
            accO[mi][dsub] = __builtin_amdgcn_mfma_f32_16x16x32_f16(ap[mi][kh], bvv, accO[mi][dsub], 0, 0, 0);
        }
    }
    __syncthreads();
  }
  // epilogue: O /= l, store f16 (B,T,D)
  size_t orow = ((size_t)b * TT + qt * 128 + w * 32) * DD + h * 64;
#pragma unroll
  for (int mi = 0; mi < 2; ++mi)
#pragma unroll
    for (int r = 0; r < 4; ++r) {
      float lo = __shfl(l_run[mi], quad * 4 + r);
      float rl = 1.0f / lo;
      int t = mi * 16 + quad * 4 + r;
#pragma unroll
      for (int dsub = 0; dsub < 4; ++dsub)
        wv[orow + (size_t)t * DD + dsub * 16 + col16] = (f16)(accO[mi][dsub][r] * rl);
    }
}

// ---------------------------------------------------------------------------
// GEMM2: out = wv(f16 MxK) x Wo_t(f16 NxK) + bo, fp32 out. Same m97 core.
// ---------------------------------------------------------------------------
__global__ __launch_bounds__(256) void gemm_out(const f16* __restrict__ A,
                                                const f16* __restrict__ Wt,
                                                const float* __restrict__ bo,
                                                float* __restrict__ out) {
  __shared__ f16 As[128 * 64];
  __shared__ f16 Bs[128 * 64];
  int tid = threadIdx.x, w = tid >> 6, lane = tid & 63;
  int m0 = blockIdx.y * 128, n0 = blockIdx.x * 128;
  int col16 = lane & 15, quad = lane >> 4;
  int wm = (w >> 1) * 64, wn = (w & 1) * 64;
  int rowS[4], cgS[4];
#pragma unroll
  for (int t = 0; t < 4; ++t) {
    int L = w * 256 + t * 64 + lane;
    rowS[t] = L >> 3;
    cgS[t] = (L & 7) ^ ((L >> 3) & 7);
  }
  f32x4 acc[4][4] = {};
  for (int k0 = 0; k0 < DD; k0 += 64) {
#pragma unroll
    for (int t = 0; t < 4; ++t) {
      async16(&A[(size_t)(m0 + rowS[t]) * DD + k0 + cgS[t] * 8], &As[(w * 4 + t) * 512]);
      async16(&Wt[(size_t)(n0 + rowS[t]) * DD + k0 + cgS[t] * 8], &Bs[(w * 4 + t) * 512]);
    }
    __syncthreads();
    f16x8 af[4][2], bf[4][2];
#pragma unroll
    for (int mi = 0; mi < 4; ++mi) {
      int m = wm + mi * 16 + col16;
#pragma unroll
      for (int kh = 0; kh < 2; ++kh)
        af[mi][kh] = *(f16x8*)&As[m * 64 + (((kh * 4 + quad) ^ (m & 7)) * 8)];
    }
#pragma unroll
    for (int ni = 0; ni < 4; ++ni) {
      int n = wn + ni * 16 + col16;
#pragma unroll
      for (int kh = 0; kh < 2; ++kh)
        bf[ni][kh] = *(f16x8*)&Bs[n * 64 + (((kh * 4 + quad) ^ (n & 7)) * 8)];
    }
#pragma unroll
    for (int kh = 0; kh < 2; ++kh)
#pragma unroll
      for (int mi = 0; mi < 4; ++mi)
#pragma unroll
        for (int ni = 0; ni < 4; ++ni)
          acc[mi][ni] = __builtin_amdgcn_mfma_f32_16x16x32_f16(af[mi][kh], bf[ni][kh], acc[mi][ni], 0, 0, 0);
    __syncthreads();
  }
#pragma unroll
  for (int mi = 0; mi < 4; ++mi)
#pragma unroll
    for (int ni = 0; ni < 4; ++ni) {
      int n = n0 + wn + ni * 16 + col16;
      float bias = bo[n];
      size_t mrow = (size_t)(m0 + wm + mi * 16 + quad * 4) * DD + n;
#pragma unroll
      for (int r = 0; r < 4; ++r)
        out[mrow + (size_t)r * DD] = acc[mi][ni][r] + bias;
    }
}

// ---------------------------------------------------------------------------
extern "C" void kernel_launch(void* const* d_in, const int* in_sizes, int n_in,
                              void* d_out, int out_size, void* d_ws, size_t ws_size,
                              hipStream_t stream) {
  const float* x  = (const float*)d_in[0];
  const float* Wq = (const float*)d_in[4];
  const float* bq = (const float*)d_in[5];
  const float* Wk = (const float*)d_in[6];
  const float* Wv = (const float*)d_in[7];
  const float* bv = (const float*)d_in[8];
  const float* Wo = (const float*)d_in[9];
  const float* bo = (const float*)d_in[10];

  float* out  = (float*)d_out;
  float* kout = out + (size_t)MM * DD;
  float* vout = out + 2 * (size_t)MM * DD;

  // ws layout (bytes):
  //   wqkv_t : 9,830,400   (3x 1280x1280 f16, transposed)
  //   wo_t   : 3,276,800
  //   xf16/wv: 20,971,520  (aliased: xf16 dead after gemm_qkv; wv written by attn)
  //   qbuf   : 20,971,520  (f16 [b][h][t][d], scale folded)
  //   vt16   : 20,971,520  (optional f16 [b][h][d][t], only if ws_size permits)
  char* ws = (char*)d_ws;
  f16* wqkv_t = (f16*)(ws);
  f16* wo_t   = (f16*)(ws + 9830400);
  f16* xf16   = (f16*)(ws + 13107200);
  f16* wvbuf  = (f16*)(ws + 13107200);   // alias with xf16 (phases disjoint)
  f16* qbuf   = (f16*)(ws + 34078720);
  f16* vt16   = (f16*)(ws + 55050240);
  int use_vt = (ws_size >= (size_t)76021760) ? 1 : 0;

  dim3 tb(32, 8), tg(40, 40);
  transpose_cast<<<tg, tb, 0, stream>>>(Wq, wqkv_t);
  transpose_cast<<<tg, tb, 0, stream>>>(Wk, wqkv_t + 1280 * 1280);
  transpose_cast<<<tg, tb, 0, stream>>>(Wv, wqkv_t + 2 * 1280 * 1280);
  transpose_cast<<<tg, tb, 0, stream>>>(Wo, wo_t);
  cvt_x<<<MM * DD / (256 * 8), 256, 0, stream>>>(x, xf16);

  gemm_qkv<<<dim3(30, 64), 256, 0, stream>>>(xf16, wqkv_t, bq, bv, qbuf, kout, vout, vt16, use_vt);
  attn<<<dim3(8, HH, BB), 256, 0, stream>>>(qbuf, kout, vout, vt16, wvbuf, use_vt);
  gemm_out<<<dim3(10, 64), 256, 0, stream>>>(wvbuf, wo_t, bo, out);
}

// Round 3
// 482.947 us; speedup vs baseline: 1.3730x; 1.0490x over previous
//
#include <hip/hip_runtime.h>

// Whisper-style self-attention, B=8 T=1024 D=1280 H=20 DH=64, fp32 I/O.
#define BB 8
#define TT 1024
#define DD 1280
#define HH 20
#define DHH 64
#define MM (BB*TT)      // 8192 rows

typedef _Float16 f16;
typedef f16 f16x8 __attribute__((ext_vector_type(8)));
typedef f16 f16x4 __attribute__((ext_vector_type(4)));
typedef float f32x4 __attribute__((ext_vector_type(4)));

// async global->LDS, 16B per lane. LDS dest = wave-uniform base + lane*16.
__device__ __forceinline__ void async16(const f16* g, f16* l) {
  __builtin_amdgcn_global_load_lds((const __attribute__((address_space(1))) void*)g,
                                   (__attribute__((address_space(3))) void*)l, 16, 0, 0);
}

// ---------------------------------------------------------------------------
// Fused weight transpose + fp32->f16 cast for Wq,Wk,Wv,Wo (blockIdx.z picks)
// ---------------------------------------------------------------------------
__global__ __launch_bounds__(256) void transpose_cast4(const float* __restrict__ Wq,
                                                       const float* __restrict__ Wk,
                                                       const float* __restrict__ Wv,
                                                       const float* __restrict__ Wo,
                                                       f16* __restrict__ wqkv_t,
                                                       f16* __restrict__ wo_t) {
  __shared__ float tile[32][33];
  int z = blockIdx.z;
  const float* W = (z == 0) ? Wq : (z == 1) ? Wk : (z == 2) ? Wv : Wo;
  f16* Wt = (z < 3) ? (wqkv_t + (size_t)z * DD * DD) : wo_t;
  int tx = threadIdx.x, ty = threadIdx.y;
  int n0 = blockIdx.x * 32, k0 = blockIdx.y * 32;
#pragma unroll
  for (int i = 0; i < 32; i += 8)
    tile[ty + i][tx] = W[(size_t)(k0 + ty + i) * DD + n0 + tx];
  __syncthreads();
#pragma unroll
  for (int i = 0; i < 32; i += 8)
    Wt[(size_t)(n0 + ty + i) * DD + k0 + tx] = (f16)tile[tx][ty + i];
}

// ---------------------------------------------------------------------------
// x fp32 -> f16 row-major copy
// ---------------------------------------------------------------------------
__global__ __launch_bounds__(256) void cvt_x(const float* __restrict__ src,
                                             f16* __restrict__ dst) {
  int i = blockIdx.x * 256 + threadIdx.x;   // 8 elems per thread
  float4 a = *(const float4*)&src[(size_t)i * 8];
  float4 b = *(const float4*)&src[(size_t)i * 8 + 4];
  f16x8 h = {(f16)a.x,(f16)a.y,(f16)a.z,(f16)a.w,(f16)b.x,(f16)b.y,(f16)b.z,(f16)b.w};
  *(f16x8*)&dst[(size_t)i * 8] = h;
}

// ---------------------------------------------------------------------------
// GEMM1: m97-style core, 128x128 tile, BK=64, global_load_lds, XOR-swizzled
// LDS. Epilogue: q -> qbuf f16 [b][h][t][d] (scale folded); k -> k_cache fp32
// (+ kt16 f16 [b][h][t][d]); v -> v_cache fp32 +bv (+ vt16 f16 [b][h][d][t]).
// ---------------------------------------------------------------------------
__global__ __launch_bounds__(256, 4) void gemm_qkv(const f16* __restrict__ Xh,
                                                   const f16* __restrict__ Wt,
                                                   const float* __restrict__ bq,
                                                   const float* __restrict__ bv,
                                                   f16* __restrict__ qbuf,
                                                   float* __restrict__ kout,
                                                   float* __restrict__ vout,
                                                   f16* __restrict__ kt16,
                                                   f16* __restrict__ vt16,
                                                   int use_f16) {
  __shared__ f16 As[128 * 64];
  __shared__ f16 Bs[128 * 64];
  int tid = threadIdx.x, w = tid >> 6, lane = tid & 63;
  int m0 = blockIdx.y * 128, n0 = blockIdx.x * 128;
  int col16 = lane & 15, quad = lane >> 4;
  int wm = (w >> 1) * 64, wn = (w & 1) * 64;
  int rowS[4], cgS[4];
#pragma unroll
  for (int t = 0; t < 4; ++t) {
    int L = w * 256 + t * 64 + lane;
    rowS[t] = L >> 3;
    cgS[t] = (L & 7) ^ ((L >> 3) & 7);
  }
  f32x4 acc[4][4] = {};
  for (int k0 = 0; k0 < DD; k0 += 64) {
#pragma unroll
    for (int t = 0; t < 4; ++t) {
      async16(&Xh[(size_t)(m0 + rowS[t]) * DD + k0 + cgS[t] * 8], &As[(w * 4 + t) * 512]);
      async16(&Wt[(size_t)(n0 + rowS[t]) * DD + k0 + cgS[t] * 8], &Bs[(w * 4 + t) * 512]);
    }
    __syncthreads();
    f16x8 af[4][2], bf[4][2];
#pragma unroll
    for (int mi = 0; mi < 4; ++mi) {
      int m = wm + mi * 16 + col16;
#pragma unroll
      for (int kh = 0; kh < 2; ++kh)
        af[mi][kh] = *(f16x8*)&As[m * 64 + (((kh * 4 + quad) ^ (m & 7)) * 8)];
    }
#pragma unroll
    for (int ni = 0; ni < 4; ++ni) {
      int n = wn + ni * 16 + col16;
#pragma unroll
      for (int kh = 0; kh < 2; ++kh)
        bf[ni][kh] = *(f16x8*)&Bs[n * 64 + (((kh * 4 + quad) ^ (n & 7)) * 8)];
    }
#pragma unroll
    for (int kh = 0; kh < 2; ++kh)
#pragma unroll
      for (int mi = 0; mi < 4; ++mi)
#pragma unroll
        for (int ni = 0; ni < 4; ++ni)
          acc[mi][ni] = __builtin_amdgcn_mfma_f32_16x16x32_f16(af[mi][kh], bf[ni][kh], acc[mi][ni], 0, 0, 0);
    __syncthreads();
  }

  int region = n0 / DD, nb = n0 - region * DD;
  int bB = m0 >> 10;            // 128-row tiles never cross a batch boundary
  int t0 = m0 & 1023;
  if (region == 0) {            // q
#pragma unroll
    for (int mi = 0; mi < 4; ++mi)
#pragma unroll
      for (int ni = 0; ni < 4; ++ni) {
        int n = nb + wn + ni * 16 + col16;
        int hh = n >> 6, dd = n & 63;
        float bb = bq[n];
        size_t base = (((size_t)bB * HH + hh) * TT + (t0 + wm + mi * 16 + quad * 4)) * 64 + dd;
#pragma unroll
        for (int r = 0; r < 4; ++r)
          qbuf[base + (size_t)r * 64] = (f16)((acc[mi][ni][r] + bb) * 0.125f);
      }
  } else if (region == 1) {     // k
#pragma unroll
    for (int mi = 0; mi < 4; ++mi)
#pragma unroll
      for (int ni = 0; ni < 4; ++ni) {
        int n = nb + wn + ni * 16 + col16;
        int hh = n >> 6, dd = n & 63;
        size_t mrow = (size_t)(m0 + wm + mi * 16 + quad * 4) * DD + n;
        size_t base = (((size_t)bB * HH + hh) * TT + (t0 + wm + mi * 16 + quad * 4)) * 64 + dd;
#pragma unroll
        for (int r = 0; r < 4; ++r) {
          float vv = acc[mi][ni][r];
          kout[mrow + (size_t)r * DD] = vv;
          if (use_f16) kt16[base + (size_t)r * 64] = (f16)vv;
        }
      }
  } else {                      // v
#pragma unroll
    for (int mi = 0; mi < 4; ++mi)
#pragma unroll
      for (int ni = 0; ni < 4; ++ni) {
        int n = nb + wn + ni * 16 + col16;
        int hh = n >> 6, dd = n & 63;
        float bb = bv[n];
        size_t mrow = (size_t)(m0 + wm + mi * 16 + quad * 4) * DD + n;
        f16x4 pk;
#pragma unroll
        for (int r = 0; r < 4; ++r) {
          float vv = acc[mi][ni][r] + bb;
          vout[mrow + (size_t)r * DD] = vv;
          pk[r] = (f16)vv;
        }
        if (use_f16)
          *(f16x4*)&vt16[(((size_t)bB * HH + hh) * 64 + dd) * TT + t0 + wm + mi * 16 + quad * 4] = pk;
      }
  }
}

// ---------------------------------------------------------------------------
// Flash attention v3: grid (8,20,8), 4 waves, 128 q-rows/block (32/wave),
// heavy tiles first (qt = 7 - blockIdx.x). K/V staged via global_load_lds
// from f16 copies into XOR-swizzled unpadded LDS (fallback: VALU convert
// from fp32, same swizzled layout). S^T = K*Q^T; softmax in-register;
// P through swizzled LDS once.
// ---------------------------------------------------------------------------
__global__ __launch_bounds__(256) void attn(const f16* __restrict__ qbuf,
                                            const f16* __restrict__ kt16,
                                            const f16* __restrict__ vt16,
                                            const float* __restrict__ kout,
                                            const float* __restrict__ vout,
                                            f16* __restrict__ wv,
                                            int use_f16) {
  __shared__ f16 Ks[64 * 64];       // row j, swizzled chunks
  __shared__ f16 Vt[64 * 64];       // row d, swizzled chunks
  __shared__ f16 Pw[4][32 * 64];    // per-wave P[q][j], swizzled
  int qt = 7 - (int)blockIdx.x, h = blockIdx.y, b = blockIdx.z;
  int tid = threadIdx.x, w = tid >> 6, lane = tid & 63;
  int col16 = lane & 15, quad = lane >> 4;
  int c7 = col16 & 7;

  const f16* Qh = qbuf + (((size_t)b * HH + h) * TT + qt * 128 + w * 32) * 64;
  f16x8 qf[2][2];
#pragma unroll
  for (int ni = 0; ni < 2; ++ni)
#pragma unroll
    for (int kh = 0; kh < 2; ++kh)
      qf[ni][kh] = *(const f16x8*)&Qh[(ni * 16 + col16) * 64 + kh * 32 + quad * 8];

  float m_run[2] = {-1e30f, -1e30f}, l_run[2] = {0.f, 0.f};
  f32x4 accO[2][4] = {};
  int jt_end = 2 * qt + 2;
  int my_end = 2 * qt + 1 + (w >> 1);
  const f16* Ktg = kt16 + (((size_t)b * HH + h) * TT) * 64;
  const f16* Vtg = vt16 + (((size_t)b * HH + h) * 64) * TT;
  const float* Kg = kout + ((size_t)b * TT) * DD + h * 64;
  const float* Vg = vout + ((size_t)b * TT) * DD + h * 64;

  for (int jt = 0; jt < jt_end; ++jt) {
    if (use_f16) {
      // async16 staging: per wave, 16 rows (2 calls of 8 rows)
#pragma unroll
      for (int t = 0; t < 2; ++t) {
        int j = w * 16 + t * 8 + (lane >> 3);
        int cg = (lane & 7) ^ (j & 7);
        async16(&Ktg[(size_t)(jt * 64 + j) * 64 + cg * 8], &Ks[w * 1024 + t * 512]);
        int d = j;
        async16(&Vtg[(size_t)d * TT + jt * 64 + cg * 8], &Vt[w * 1024 + t * 512]);
      }
    } else {
#pragma unroll
      for (int i = 0; i < 4; ++i) {
        int g = tid + i * 256;
        int j = g >> 4, c4 = (g & 15) * 4;
        float4 kv = *(const float4*)&Kg[(size_t)(jt * 64 + j) * DD + c4];
        f16x4 k4 = {(f16)kv.x, (f16)kv.y, (f16)kv.z, (f16)kv.w};
        *(f16x4*)&Ks[j * 64 + (((c4 >> 3) ^ (j & 7)) * 8) + (c4 & 7)] = k4;
        float4 vv = *(const float4*)&Vg[(size_t)(jt * 64 + j) * DD + c4];
        int ch = (j >> 3), jo = j & 7;
        Vt[(c4 + 0) * 64 + ((ch ^ ((c4 + 0) & 7)) * 8) + jo] = (f16)vv.x;
        Vt[(c4 + 1) * 64 + ((ch ^ ((c4 + 1) & 7)) * 8) + jo] = (f16)vv.y;
        Vt[(c4 + 2) * 64 + ((ch ^ ((c4 + 2) & 7)) * 8) + jo] = (f16)vv.z;
        Vt[(c4 + 3) * 64 + ((ch ^ ((c4 + 3) & 7)) * 8) + jo] = (f16)vv.w;
      }
    }
    __syncthreads();

    if (jt < my_end) {
      // S^T[j][q] = K*Q^T : C row=j (quad*4+r), col=q (col16)
      f32x4 s[4][2] = {};
#pragma unroll
      for (int mj = 0; mj < 4; ++mj)
#pragma unroll
        for (int kh = 0; kh < 2; ++kh) {
          f16x8 ak = *(f16x8*)&Ks[(mj * 16 + col16) * 64 + (((kh * 4 + quad) ^ c7) * 8)];
#pragma unroll
          for (int ni = 0; ni < 2; ++ni)
            s[mj][ni] = __builtin_amdgcn_mfma_f32_16x16x32_f16(ak, qf[ni][kh], s[mj][ni], 0, 0, 0);
        }
      // causal mask
      if (jt * 64 + 63 > qt * 128 + w * 32) {
#pragma unroll
        for (int mj = 0; mj < 4; ++mj)
#pragma unroll
          for (int ni = 0; ni < 2; ++ni) {
            int qg = qt * 128 + w * 32 + ni * 16 + col16;
#pragma unroll
            for (int r = 0; r < 4; ++r) {
              int jg = jt * 64 + mj * 16 + quad * 4 + r;
              if (jg > qg) s[mj][ni][r] = -1e30f;
            }
          }
      }
      // online softmax, in-register
      float alpha[2];
#pragma unroll
      for (int ni = 0; ni < 2; ++ni) {
        float mx = -1e30f;
#pragma unroll
        for (int mj = 0; mj < 4; ++mj)
#pragma unroll
          for (int r = 0; r < 4; ++r) mx = fmaxf(mx, s[mj][ni][r]);
        mx = fmaxf(mx, __shfl_xor(mx, 16));
        mx = fmaxf(mx, __shfl_xor(mx, 32));
        float mnew = fmaxf(m_run[ni], mx);
        float al = __expf(m_run[ni] - mnew);
        float ssum = 0.f;
#pragma unroll
        for (int mj = 0; mj < 4; ++mj)
#pragma unroll
          for (int r = 0; r < 4; ++r) {
            float p = __expf(s[mj][ni][r] - mnew);
            ssum += p;
            int j = mj * 16 + quad * 4 + r;
            Pw[w][(ni * 16 + col16) * 64 + (((j >> 3) ^ c7) * 8) + (j & 7)] = (f16)p;
          }
        ssum += __shfl_xor(ssum, 16);
        ssum += __shfl_xor(ssum, 32);
        l_run[ni] = l_run[ni] * al + ssum;
        m_run[ni] = mnew;
        alpha[ni] = al;
      }
      // rescale O rows
#pragma unroll
      for (int mi = 0; mi < 2; ++mi)
#pragma unroll
        for (int r = 0; r < 4; ++r) {
          float a_o = __shfl(alpha[mi], quad * 4 + r);
#pragma unroll
          for (int dsub = 0; dsub < 4; ++dsub) accO[mi][dsub][r] *= a_o;
        }
      // O += P*V
      f16x8 ap[2][2];
#pragma unroll
      for (int mi = 0; mi < 2; ++mi)
#pragma unroll
        for (int kh = 0; kh < 2; ++kh)
          ap[mi][kh] = *(f16x8*)&Pw[w][(mi * 16 + col16) * 64 + (((kh * 4 + quad) ^ c7) * 8)];
#pragma unroll
      for (int dsub = 0; dsub < 4; ++dsub)
#pragma unroll
        for (int kh = 0; kh < 2; ++kh) {
          f16x8 bvv = *(f16x8*)&Vt[(dsub * 16 + col16) * 64 + (((kh * 4 + quad) ^ c7) * 8)];
#pragma unroll
          for (int mi = 0; mi < 2; ++mi)
            accO[mi][dsub] = __builtin_amdgcn_mfma_f32_16x16x32_f16(ap[mi][kh], bvv, accO[mi][dsub], 0, 0, 0);
        }
    }
    __syncthreads();
  }
  // epilogue: O /= l, store f16 (B,T,D)
  size_t orow = ((size_t)b * TT + qt * 128 + w * 32) * DD + h * 64;
#pragma unroll
  for (int mi = 0; mi < 2; ++mi)
#pragma unroll
    for (int r = 0; r < 4; ++r) {
      float lo = __shfl(l_run[mi], quad * 4 + r);
      float rl = 1.0f / lo;
      int t = mi * 16 + quad * 4 + r;
#pragma unroll
      for (int dsub = 0; dsub < 4; ++dsub)
        wv[orow + (size_t)t * DD + dsub * 16 + col16] = (f16)(accO[mi][dsub][r] * rl);
    }
}

// ---------------------------------------------------------------------------
// GEMM2: out = wv(f16 MxK) x Wo_t(f16 NxK) + bo, fp32 out. Same m97 core.
// ---------------------------------------------------------------------------
__global__ __launch_bounds__(256, 4) void gemm_out(const f16* __restrict__ A,
                                                   const f16* __restrict__ Wt,
                                                   const float* __restrict__ bo,
                                                   float* __restrict__ out) {
  __shared__ f16 As[128 * 64];
  __shared__ f16 Bs[128 * 64];
  int tid = threadIdx.x, w = tid >> 6, lane = tid & 63;
  int m0 = blockIdx.y * 128, n0 = blockIdx.x * 128;
  int col16 = lane & 15, quad = lane >> 4;
  int wm = (w >> 1) * 64, wn = (w & 1) * 64;
  int rowS[4], cgS[4];
#pragma unroll
  for (int t = 0; t < 4; ++t) {
    int L = w * 256 + t * 64 + lane;
    rowS[t] = L >> 3;
    cgS[t] = (L & 7) ^ ((L >> 3) & 7);
  }
  f32x4 acc[4][4] = {};
  for (int k0 = 0; k0 < DD; k0 += 64) {
#pragma unroll
    for (int t = 0; t < 4; ++t) {
      async16(&A[(size_t)(m0 + rowS[t]) * DD + k0 + cgS[t] * 8], &As[(w * 4 + t) * 512]);
      async16(&Wt[(size_t)(n0 + rowS[t]) * DD + k0 + cgS[t] * 8], &Bs[(w * 4 + t) * 512]);
    }
    __syncthreads();
    f16x8 af[4][2], bf[4][2];
#pragma unroll
    for (int mi = 0; mi < 4; ++mi) {
      int m = wm + mi * 16 + col16;
#pragma unroll
      for (int kh = 0; kh < 2; ++kh)
        af[mi][kh] = *(f16x8*)&As[m * 64 + (((kh * 4 + quad) ^ (m & 7)) * 8)];
    }
#pragma unroll
    for (int ni = 0; ni < 4; ++ni) {
      int n = wn + ni * 16 + col16;
#pragma unroll
      for (int kh = 0; kh < 2; ++kh)
        bf[ni][kh] = *(f16x8*)&Bs[n * 64 + (((kh * 4 + quad) ^ (n & 7)) * 8)];
    }
#pragma unroll
    for (int kh = 0; kh < 2; ++kh)
#pragma unroll
      for (int mi = 0; mi < 4; ++mi)
#pragma unroll
        for (int ni = 0; ni < 4; ++ni)
          acc[mi][ni] = __builtin_amdgcn_mfma_f32_16x16x32_f16(af[mi][kh], bf[ni][kh], acc[mi][ni], 0, 0, 0);
    __syncthreads();
  }
#pragma unroll
  for (int mi = 0; mi < 4; ++mi)
#pragma unroll
    for (int ni = 0; ni < 4; ++ni) {
      int n = n0 + wn + ni * 16 + col16;
      float bias = bo[n];
      size_t mrow = (size_t)(m0 + wm + mi * 16 + quad * 4) * DD + n;
#pragma unroll
      for (int r = 0; r < 4; ++r)
        out[mrow + (size_t)r * DD] = acc[mi][ni][r] + bias;
    }
}

// ---------------------------------------------------------------------------
extern "C" void kernel_launch(void* const* d_in, const int* in_sizes, int n_in,
                              void* d_out, int out_size, void* d_ws, size_t ws_size,
                              hipStream_t stream) {
  const float* x  = (const float*)d_in[0];
  const float* Wq = (const float*)d_in[4];
  const float* bq = (const float*)d_in[5];
  const float* Wk = (const float*)d_in[6];
  const float* Wv = (const float*)d_in[7];
  const float* bv = (const float*)d_in[8];
  const float* Wo = (const float*)d_in[9];
  const float* bo = (const float*)d_in[10];

  float* out  = (float*)d_out;
  float* kout = out + (size_t)MM * DD;
  float* vout = out + 2 * (size_t)MM * DD;

  // ws layout (bytes):
  //   wqkv_t : 0          (9,830,400)
  //   wo_t   : 9,830,400  (3,276,800)
  //   xf16/wv: 13,107,200 (20,971,520)  aliased, phases disjoint
  //   qbuf   : 34,078,720 (20,971,520)
  //   vt16   : 55,050,240 (20,971,520)
  //   kt16   : 76,021,760 (20,971,520)  -> total 96,993,280
  char* ws = (char*)d_ws;
  f16* wqkv_t = (f16*)(ws);
  f16* wo_t   = (f16*)(ws + 9830400);
  f16* xf16   = (f16*)(ws + 13107200);
  f16* wvbuf  = (f16*)(ws + 13107200);
  f16* qbuf   = (f16*)(ws + 34078720);
  f16* vt16   = (f16*)(ws + 55050240);
  f16* kt16   = (f16*)(ws + 76021760);
  int use_f16 = (ws_size >= (size_t)96993280) ? 1 : 0;

  transpose_cast4<<<dim3(40, 40, 4), dim3(32, 8), 0, stream>>>(Wq, Wk, Wv, Wo, wqkv_t, wo_t);
  cvt_x<<<MM * DD / (256 * 8), 256, 0, stream>>>(x, xf16);

  gemm_qkv<<<dim3(30, 64), 256, 0, stream>>>(xf16, wqkv_t, bq, bv, qbuf, kout, vout, kt16, vt16, use_f16);
  attn<<<dim3(8, HH, BB), 256, 0, stream>>>(qbuf, kt16, vt16, kout, vout, wvbuf, use_f16);
  gemm_out<<<dim3(10, 64), 256, 0, stream>>>(wvbuf, wo_t, bo, out);
}